// Round 4
// baseline (91.172 us; speedup 1.0000x reference)
//
#include <hip/hip_runtime.h>
#include <math.h>

#define BB 8
#define CC 512
#define HWSZ 6400
#define NN 100
#define HR 40
#define WR 40
#define VV 20        // N_CLASSES_FG
#define VO 21        // BG + FG
#define TPX 256      // pixels per tile (1KB contiguous per channel row)
#define NT (HWSZ / TPX)      // 25 tiles per batch image
#define KB 32        // channels per staged batch
#define NKB (CC / KB)        // 16 batches

typedef unsigned long long u64;

// order-preserving float -> uint32 map (min float == min uint)
__device__ __forceinline__ unsigned mapf(float f) {
    unsigned b = __float_as_uint(f);
    return (b & 0x80000000u) ? ~b : (b | 0x80000000u);
}

// async global -> LDS, 16B per lane; lp must be wave-uniform (HW adds lane*16)
__device__ __forceinline__ void gload16(const float* gp, const float* lp) {
    __builtin_amdgcn_global_load_lds(
        (const __attribute__((address_space(1))) void*)gp,
        (__attribute__((address_space(3))) void*)lp, 16, 0, 0);
}

// ---------------- K1: normalized prototypes, transposed [c][v]; init batchMin
__global__ __launch_bounds__(512) void k_protos(const float* __restrict__ refc,
                                                const int* __restrict__ coord,
                                                const int* __restrict__ cls,
                                                float* __restrict__ protosT,
                                                u64* __restrict__ batchMin) {
    const int v = blockIdx.x;        // class
    const int c = threadIdx.x;       // channel
    if (v == 0 && c < BB) batchMin[c] = ~0ull;

    float acc = 0.f;
    int cnt = 0;
    for (int n = 0; n < NN; ++n) {
        if (cls[n] == v) {           // uniform across block
            int y = coord[2 * n + 1];
            int x = coord[2 * n + 0];
            acc += refc[((size_t)(n * CC + c) * HR + y) * WR + x];
            ++cnt;
        }
    }
    acc /= fmaxf((float)cnt, 1.0f);

    float ss = acc * acc;
    #pragma unroll
    for (int off = 32; off; off >>= 1) ss += __shfl_xor(ss, off);
    __shared__ float sW[8];
    const int wave = c >> 6, lane = c & 63;
    if (lane == 0) sW[wave] = ss;
    __syncthreads();
    float tot = 0.f;
    #pragma unroll
    for (int w = 0; w < 8; ++w) tot += sW[w];
    float scale = 1.0f / fmaxf(sqrtf(tot), 1e-10f);

    protosT[c * VV + v] = acc * scale;
}

// ---------------- K2: staged prob_C + per-pixel sum + fused argmin ----------
// grid = 8 b x 25 tiles(256 px); block = 256 = 4 waves.
// Stage [32ch x 256px] (32KB) via global_load_lds(16B), double-buffered.
// Wave w computes channels w*8..w*8+7 of each batch; lane owns 4 px.
__global__ __launch_bounds__(256, 2) void k_probC(const float* __restrict__ codeC,
                                                  const float* __restrict__ protosT,
                                                  float* __restrict__ probC,
                                                  u64* __restrict__ batchMin) {
    __shared__ float stage[2][KB * TPX];   // 64 KB; aliased as redA in epilogue
    __shared__ u64 sKey[4];

    const int tid  = threadIdx.x;
    const int w    = tid >> 6, lane = tid & 63;
    const int b    = blockIdx.x / NT;
    const int tile = blockIdx.x % NT;
    const int c0w  = __builtin_amdgcn_readfirstlane(w * 8);

    const float* gbase = codeC + (size_t)b * CC * HWSZ + tile * TPX;

    float d[VV][4];
    #pragma unroll
    for (int v = 0; v < VV; ++v) { d[v][0] = d[v][1] = d[v][2] = d[v][3] = 0.f; }
    float ss0 = 0.f, ss1 = 0.f, ss2 = 0.f, ss3 = 0.f;

    // prologue: stage batch 0
    #pragma unroll
    for (int k = 0; k < 8; ++k) {
        int r = 4 * k + w;
        gload16(gbase + (size_t)r * HWSZ + lane * 4, &stage[0][r * TPX]);
    }
    __syncthreads();

    int buf = 0;
    for (int t = 0; t < NKB; ++t) {
        if (t < NKB - 1) {
            #pragma unroll
            for (int k = 0; k < 8; ++k) {
                int r = 4 * k + w;
                gload16(gbase + (size_t)((t + 1) * KB + r) * HWSZ + lane * 4,
                        &stage[buf ^ 1][r * TPX]);
            }
        }
        const float* pt = protosT + (size_t)(t * KB + c0w) * VV;
        #pragma unroll
        for (int j = 0; j < 8; ++j) {
            float4 x = *(const float4*)&stage[buf][(w * 8 + j) * TPX + lane * 4];
            ss0 = fmaf(x.x, x.x, ss0);
            ss1 = fmaf(x.y, x.y, ss1);
            ss2 = fmaf(x.z, x.z, ss2);
            ss3 = fmaf(x.w, x.w, ss3);
            const float* pr = pt + j * VV;
            #pragma unroll
            for (int v = 0; v < VV; ++v) {
                float p = pr[v];
                d[v][0] = fmaf(x.x, p, d[v][0]);
                d[v][1] = fmaf(x.y, p, d[v][1]);
                d[v][2] = fmaf(x.z, p, d[v][2]);
                d[v][3] = fmaf(x.w, p, d[v][3]);
            }
        }
        __syncthreads();
        buf ^= 1;
    }

    // ---- epilogue: cross-wave reduce in 2 rounds of 11/10 rows (reuse stage)
    float* redA = &stage[0][0];          // [4][11][256] = 45 KB
    const int px = tid;                  // 0..255
    float* dst = probC + (size_t)b * VV * HWSZ + tile * TPX;

    // round A: ss + d0..d9
    *(float4*)&redA[(w * 11 + 0) * TPX + lane * 4] = make_float4(ss0, ss1, ss2, ss3);
    #pragma unroll
    for (int v = 0; v < 10; ++v)
        *(float4*)&redA[(w * 11 + 1 + v) * TPX + lane * 4] =
            make_float4(d[v][0], d[v][1], d[v][2], d[v][3]);
    __syncthreads();

    float ssT = redA[(0 * 11) * TPX + px] + redA[(1 * 11) * TPX + px] +
                redA[(2 * 11) * TPX + px] + redA[(3 * 11) * TPX + px];
    float scale = 1.0f / fmaxf(sqrtf(ssT), 1e-10f);
    float psum = 0.f;
    #pragma unroll
    for (int v = 0; v < 10; ++v) {
        float dv = redA[(0 * 11 + 1 + v) * TPX + px] + redA[(1 * 11 + 1 + v) * TPX + px] +
                   redA[(2 * 11 + 1 + v) * TPX + px] + redA[(3 * 11 + 1 + v) * TPX + px];
        float p = dv * scale;
        dst[(size_t)v * HWSZ + px] = p;
        psum += p;
    }
    __syncthreads();

    // round B: d10..d19
    #pragma unroll
    for (int v = 0; v < 10; ++v)
        *(float4*)&redA[(w * 11 + v) * TPX + lane * 4] =
            make_float4(d[10 + v][0], d[10 + v][1], d[10 + v][2], d[10 + v][3]);
    __syncthreads();
    #pragma unroll
    for (int v = 0; v < 10; ++v) {
        float dv = redA[(0 * 11 + v) * TPX + px] + redA[(1 * 11 + v) * TPX + px] +
                   redA[(2 * 11 + v) * TPX + px] + redA[(3 * 11 + v) * TPX + px];
        float p = dv * scale;
        dst[(size_t)(10 + v) * HWSZ + px] = p;
        psum += p;
    }

    // ---- fused argmin (deterministic)
    u64 key = ((u64)mapf(psum) << 32) | (unsigned)(tile * TPX + px);
    #pragma unroll
    for (int off = 32; off; off >>= 1) {
        u64 o = __shfl_xor(key, off);
        if (o < key) key = o;
    }
    if (lane == 0) sKey[w] = key;
    __syncthreads();
    if (tid == 0) {
        u64 kk = sKey[0];
        kk = sKey[1] < kk ? sKey[1] : kk;
        kk = sKey[2] < kk ? sKey[2] : kk;
        kk = sKey[3] < kk ? sKey[3] : kk;
        atomicMin(&batchMin[b], kk);
    }
}

// ---------------- K3: normalize code_BG at the argmin pixel -----------------
__global__ __launch_bounds__(512) void k_minvec(const u64* __restrict__ batchMin,
                                                const float* __restrict__ codeBG,
                                                float* __restrict__ minvecN) {
    const int b = blockIdx.x, c = threadIdx.x;
    const int pix = (int)(unsigned)(batchMin[b] & 0xFFFFFFFFull);
    float x = codeBG[(size_t)(b * CC + c) * HWSZ + pix];
    float ss = x * x;
    #pragma unroll
    for (int off = 32; off; off >>= 1) ss += __shfl_xor(ss, off);
    __shared__ float sW[8];
    if ((c & 63) == 0) sW[c >> 6] = ss;
    __syncthreads();
    float tot = 0.f;
    #pragma unroll
    for (int w = 0; w < 8; ++w) tot += sW[w];
    minvecN[b * CC + c] = x * (1.0f / fmaxf(sqrtf(tot), 1e-10f));
}

// ---------------- K4: staged prob_BG + fused softmax + output ---------------
__global__ __launch_bounds__(256, 2) void k_bg_softmax(const float* __restrict__ codeBG,
                                                       const float* __restrict__ minvecN,
                                                       const float* __restrict__ probC,
                                                       float* __restrict__ out) {
    __shared__ float stage[2][KB * TPX];   // 64 KB
    __shared__ float redB[8 * TPX];        // 8 KB

    const int tid  = threadIdx.x;
    const int w    = tid >> 6, lane = tid & 63;
    const int b    = blockIdx.x / NT;
    const int tile = blockIdx.x % NT;
    const int c0w  = __builtin_amdgcn_readfirstlane(w * 8);

    const float* gbase = codeBG + (size_t)b * CC * HWSZ + tile * TPX;

    float ss0 = 0.f, ss1 = 0.f, ss2 = 0.f, ss3 = 0.f;
    float dg0 = 0.f, dg1 = 0.f, dg2 = 0.f, dg3 = 0.f;

    #pragma unroll
    for (int k = 0; k < 8; ++k) {
        int r = 4 * k + w;
        gload16(gbase + (size_t)r * HWSZ + lane * 4, &stage[0][r * TPX]);
    }
    __syncthreads();

    int buf = 0;
    for (int t = 0; t < NKB; ++t) {
        if (t < NKB - 1) {
            #pragma unroll
            for (int k = 0; k < 8; ++k) {
                int r = 4 * k + w;
                gload16(gbase + (size_t)((t + 1) * KB + r) * HWSZ + lane * 4,
                        &stage[buf ^ 1][r * TPX]);
            }
        }
        const float* mv = minvecN + b * CC + t * KB + c0w;
        #pragma unroll
        for (int j = 0; j < 8; ++j) {
            float4 x = *(const float4*)&stage[buf][(w * 8 + j) * TPX + lane * 4];
            float m = mv[j];
            ss0 = fmaf(x.x, x.x, ss0);
            ss1 = fmaf(x.y, x.y, ss1);
            ss2 = fmaf(x.z, x.z, ss2);
            ss3 = fmaf(x.w, x.w, ss3);
            dg0 = fmaf(x.x, m, dg0);
            dg1 = fmaf(x.y, m, dg1);
            dg2 = fmaf(x.z, m, dg2);
            dg3 = fmaf(x.w, m, dg3);
        }
        __syncthreads();
        buf ^= 1;
    }

    *(float4*)&redB[(w * 2 + 0) * TPX + lane * 4] = make_float4(ss0, ss1, ss2, ss3);
    *(float4*)&redB[(w * 2 + 1) * TPX + lane * 4] = make_float4(dg0, dg1, dg2, dg3);
    __syncthreads();

    const int px = tid;   // 0..255
    float ssT = redB[0 * TPX + px] + redB[2 * TPX + px] + redB[4 * TPX + px] + redB[6 * TPX + px];
    float dgT = redB[1 * TPX + px] + redB[3 * TPX + px] + redB[5 * TPX + px] + redB[7 * TPX + px];
    float pbg = dgT * (1.0f / fmaxf(sqrtf(ssT), 1e-10f));

    float pv[VO];
    pv[0] = pbg;
    const float* pc = probC + (size_t)b * VV * HWSZ + tile * TPX + px;
    #pragma unroll
    for (int v = 0; v < VV; ++v) pv[v + 1] = pc[(size_t)v * HWSZ];

    float m = pv[0];
    #pragma unroll
    for (int i = 1; i < VO; ++i) m = fmaxf(m, pv[i]);
    float se = 0.f;
    #pragma unroll
    for (int i = 0; i < VO; ++i) { pv[i] = __expf(pv[i] - m); se += pv[i]; }
    float inv = 1.0f / se;

    float* dstp = out + (size_t)b * VO * HWSZ + tile * TPX + px;
    #pragma unroll
    for (int i = 0; i < VO; ++i) dstp[(size_t)i * HWSZ] = pv[i] * inv;
}

extern "C" void kernel_launch(void* const* d_in, const int* in_sizes, int n_in,
                              void* d_out, int out_size, void* d_ws, size_t ws_size,
                              hipStream_t stream) {
    const float* codeC  = (const float*)d_in[0];
    const float* codeBG = (const float*)d_in[1];
    const float* refc   = (const float*)d_in[2];
    // d_in[3] (ref_code_bg) unused by the reference
    const int* coord = (const int*)d_in[4];
    const int* cls   = (const int*)d_in[5];
    float* out = (float*)d_out;

    char* ws = (char*)d_ws;
    float* protosT  = (float*)(ws);                    // 40,960 B  [c][v]
    float* probC    = (float*)(ws + 40960);            // 4,096,000 B
    float* minvecN  = (float*)(ws + 4136960);          // 16,384 B
    u64*   batchMin = (u64*)  (ws + 4153344);          // 64 B

    k_protos    <<<dim3(VV),      dim3(512), 0, stream>>>(refc, coord, cls, protosT, batchMin);
    k_probC     <<<dim3(BB * NT), dim3(256), 0, stream>>>(codeC, protosT, probC, batchMin);
    k_minvec    <<<dim3(BB),      dim3(512), 0, stream>>>(batchMin, codeBG, minvecN);
    k_bg_softmax<<<dim3(BB * NT), dim3(256), 0, stream>>>(codeBG, minvecN, probC, out);
}

// Round 5
// 67.595 us; speedup vs baseline: 1.3488x; 1.3488x over previous
//
#include <hip/hip_runtime.h>
#include <math.h>

#define BB 8
#define CC 512
#define HWSZ 6400
#define NN 100
#define HR 40
#define WR 40
#define VV 20        // N_CLASSES_FG
#define VO 21        // BG + FG
#define TPX 256      // pixels per tile
#define NT (HWSZ / TPX)      // 25 tiles

typedef unsigned long long u64;

// order-preserving float -> uint32 map (min float == min uint)
__device__ __forceinline__ unsigned mapf(float f) {
    unsigned b = __float_as_uint(f);
    return (b & 0x80000000u) ? ~b : (b | 0x80000000u);
}

// ---------------- K1: normalized prototypes, transposed [c][v]; init batchMin
__global__ __launch_bounds__(512) void k_protos(const float* __restrict__ refc,
                                                const int* __restrict__ coord,
                                                const int* __restrict__ cls,
                                                float* __restrict__ protosT,
                                                u64* __restrict__ batchMin) {
    const int v = blockIdx.x;        // class
    const int c = threadIdx.x;       // channel
    if (v == 0 && c < BB) batchMin[c] = ~0ull;

    float acc = 0.f;
    int cnt = 0;
    for (int n = 0; n < NN; ++n) {
        if (cls[n] == v) {           // uniform across block
            int y = coord[2 * n + 1];
            int x = coord[2 * n + 0];
            acc += refc[((size_t)(n * CC + c) * HR + y) * WR + x];
            ++cnt;
        }
    }
    acc /= fmaxf((float)cnt, 1.0f);

    float ss = acc * acc;
    #pragma unroll
    for (int off = 32; off; off >>= 1) ss += __shfl_xor(ss, off);
    __shared__ float sW[8];
    const int wave = c >> 6, lane = c & 63;
    if (lane == 0) sW[wave] = ss;
    __syncthreads();
    float tot = 0.f;
    #pragma unroll
    for (int w = 0; w < 8; ++w) tot += sW[w];
    float scale = 1.0f / fmaxf(sqrtf(tot), 1e-10f);

    protosT[c * VV + v] = acc * scale;
}

// ---------------- K2: partial prob_C sums, float4 streaming -----------------
// grid = 8b x 25tiles x 2 channel-halves = 400; block = 256 = 4 waves.
// wave w owns channels [cg*256 + w*64, +64); lane owns float4 @ px 4*lane.
// Writes RAW partial sums partC[blk][21][256]  (row0 = ss, rows 1..20 = d).
__global__ __launch_bounds__(256) void k_probC_part(const float* __restrict__ codeC,
                                                    const float* __restrict__ protosT,
                                                    float* __restrict__ partC) {
    __shared__ float red[4 * 11 * TPX];   // 45 KB

    const int tid  = threadIdx.x;
    const int w    = tid >> 6, lane = tid & 63;
    const int blk  = blockIdx.x;          // b*50 + tile*2 + cg
    const int cg   = blk & 1;
    const int tile = (blk >> 1) % NT;
    const int b    = blk / (2 * NT);
    const int c0   = __builtin_amdgcn_readfirstlane(cg * 256 + w * 64);

    const float* src = codeC + ((size_t)(b * CC + c0)) * HWSZ + tile * TPX + 4 * lane;
    const float* pt  = protosT + (size_t)c0 * VV;   // wave-uniform -> s_load

    float4 d[VV];
    #pragma unroll
    for (int v = 0; v < VV; ++v) d[v] = make_float4(0.f, 0.f, 0.f, 0.f);
    float4 ss = make_float4(0.f, 0.f, 0.f, 0.f);

    #pragma unroll 8
    for (int c = 0; c < 64; ++c) {
        float4 x = *(const float4*)(src + (size_t)c * HWSZ);
        ss.x = fmaf(x.x, x.x, ss.x);
        ss.y = fmaf(x.y, x.y, ss.y);
        ss.z = fmaf(x.z, x.z, ss.z);
        ss.w = fmaf(x.w, x.w, ss.w);
        const float* pr = pt + c * VV;
        #pragma unroll
        for (int v = 0; v < VV; ++v) {
            float p = pr[v];
            d[v].x = fmaf(x.x, p, d[v].x);
            d[v].y = fmaf(x.y, p, d[v].y);
            d[v].z = fmaf(x.z, p, d[v].z);
            d[v].w = fmaf(x.w, p, d[v].w);
        }
    }

    float* dstp = partC + (size_t)blk * (VO * TPX);

    // round A: ss + d0..d9 -> part rows 0..10
    *(float4*)&red[(w * 11 + 0) * TPX + 4 * lane] = ss;
    #pragma unroll
    for (int r = 0; r < 10; ++r)
        *(float4*)&red[(w * 11 + 1 + r) * TPX + 4 * lane] = d[r];
    __syncthreads();
    for (int q = tid; q < 11 * TPX; q += 256) {
        float t = red[q] + red[11 * TPX + q] + red[22 * TPX + q] + red[33 * TPX + q];
        dstp[q] = t;
    }
    __syncthreads();

    // round B: d10..d19 -> part rows 11..20
    #pragma unroll
    for (int r = 0; r < 10; ++r)
        *(float4*)&red[(w * 11 + r) * TPX + 4 * lane] = d[10 + r];
    __syncthreads();
    for (int q = tid; q < 10 * TPX; q += 256) {
        float t = red[q] + red[11 * TPX + q] + red[22 * TPX + q] + red[33 * TPX + q];
        dstp[11 * TPX + q] = t;
    }
}

// ---------------- K2b: combine halves -> probC + psum + argmin --------------
// grid = 8b x 25tiles = 200; block = 256 (thread = pixel).
__global__ __launch_bounds__(256) void k_finishC(const float* __restrict__ partC,
                                                 float* __restrict__ probC,
                                                 u64* __restrict__ batchMin) {
    __shared__ u64 sKey[4];
    const int tid  = threadIdx.x;               // px
    const int tile = blockIdx.x % NT;
    const int b    = blockIdx.x / NT;

    const float* p0 = partC + ((size_t)(b * 2 * NT + tile * 2)) * (VO * TPX);
    const float* p1 = p0 + VO * TPX;

    float ssT = p0[tid] + p1[tid];
    float scale = 1.0f / fmaxf(sqrtf(ssT), 1e-10f);

    float psum = 0.f;
    float* dst = probC + (size_t)b * VV * HWSZ + tile * TPX;
    #pragma unroll
    for (int v = 0; v < VV; ++v) {
        float dv = p0[(1 + v) * TPX + tid] + p1[(1 + v) * TPX + tid];
        float pv = dv * scale;
        dst[(size_t)v * HWSZ + tid] = pv;
        psum += pv;
    }

    u64 key = ((u64)mapf(psum) << 32) | (unsigned)(tile * TPX + tid);
    #pragma unroll
    for (int off = 32; off; off >>= 1) {
        u64 o = __shfl_xor(key, off);
        if (o < key) key = o;
    }
    if ((tid & 63) == 0) sKey[tid >> 6] = key;
    __syncthreads();
    if (tid == 0) {
        u64 kk = sKey[0];
        kk = sKey[1] < kk ? sKey[1] : kk;
        kk = sKey[2] < kk ? sKey[2] : kk;
        kk = sKey[3] < kk ? sKey[3] : kk;
        atomicMin(&batchMin[b], kk);
    }
}

// ---------------- K3: normalize code_BG at the argmin pixel -----------------
__global__ __launch_bounds__(512) void k_minvec(const u64* __restrict__ batchMin,
                                                const float* __restrict__ codeBG,
                                                float* __restrict__ minvecN) {
    const int b = blockIdx.x, c = threadIdx.x;
    const int pix = (int)(unsigned)(batchMin[b] & 0xFFFFFFFFull);
    float x = codeBG[(size_t)(b * CC + c) * HWSZ + pix];
    float ss = x * x;
    #pragma unroll
    for (int off = 32; off; off >>= 1) ss += __shfl_xor(ss, off);
    __shared__ float sW[8];
    if ((c & 63) == 0) sW[c >> 6] = ss;
    __syncthreads();
    float tot = 0.f;
    #pragma unroll
    for (int w = 0; w < 8; ++w) tot += sW[w];
    minvecN[b * CC + c] = x * (1.0f / fmaxf(sqrtf(tot), 1e-10f));
}

// ---------------- K4: partial prob_BG sums, float4 streaming ----------------
// Same decomposition as K2. Writes partBG[blk][2][256]  (ss row, dg row).
__global__ __launch_bounds__(256) void k_bg_part(const float* __restrict__ codeBG,
                                                 const float* __restrict__ minvecN,
                                                 float* __restrict__ partBG) {
    __shared__ float red[4 * 2 * TPX];   // 8 KB

    const int tid  = threadIdx.x;
    const int w    = tid >> 6, lane = tid & 63;
    const int blk  = blockIdx.x;
    const int cg   = blk & 1;
    const int tile = (blk >> 1) % NT;
    const int b    = blk / (2 * NT);
    const int c0   = __builtin_amdgcn_readfirstlane(cg * 256 + w * 64);

    const float* src = codeBG + ((size_t)(b * CC + c0)) * HWSZ + tile * TPX + 4 * lane;
    const float* mv  = minvecN + b * CC + c0;   // wave-uniform -> s_load

    float4 ss = make_float4(0.f, 0.f, 0.f, 0.f);
    float4 dg = make_float4(0.f, 0.f, 0.f, 0.f);

    #pragma unroll 8
    for (int c = 0; c < 64; ++c) {
        float4 x = *(const float4*)(src + (size_t)c * HWSZ);
        float m = mv[c];
        ss.x = fmaf(x.x, x.x, ss.x);
        ss.y = fmaf(x.y, x.y, ss.y);
        ss.z = fmaf(x.z, x.z, ss.z);
        ss.w = fmaf(x.w, x.w, ss.w);
        dg.x = fmaf(x.x, m, dg.x);
        dg.y = fmaf(x.y, m, dg.y);
        dg.z = fmaf(x.z, m, dg.z);
        dg.w = fmaf(x.w, m, dg.w);
    }

    *(float4*)&red[(w * 2 + 0) * TPX + 4 * lane] = ss;
    *(float4*)&red[(w * 2 + 1) * TPX + 4 * lane] = dg;
    __syncthreads();

    float* dstp = partBG + (size_t)blk * (2 * TPX);
    for (int q = tid; q < 2 * TPX; q += 256) {
        float t = red[q] + red[2 * TPX + q] + red[4 * TPX + q] + red[6 * TPX + q];
        dstp[q] = t;
    }
}

// ---------------- K4b: combine halves -> prob_BG + softmax + out ------------
__global__ __launch_bounds__(256) void k_finishBG(const float* __restrict__ partBG,
                                                  const float* __restrict__ probC,
                                                  float* __restrict__ out) {
    const int tid  = threadIdx.x;               // px
    const int tile = blockIdx.x % NT;
    const int b    = blockIdx.x / NT;

    const float* q0 = partBG + ((size_t)(b * 2 * NT + tile * 2)) * (2 * TPX);
    const float* q1 = q0 + 2 * TPX;

    float ssT = q0[tid] + q1[tid];
    float dgT = q0[TPX + tid] + q1[TPX + tid];
    float pbg = dgT * (1.0f / fmaxf(sqrtf(ssT), 1e-10f));

    float pv[VO];
    pv[0] = pbg;
    const float* pc = probC + (size_t)b * VV * HWSZ + tile * TPX + tid;
    #pragma unroll
    for (int v = 0; v < VV; ++v) pv[v + 1] = pc[(size_t)v * HWSZ];

    float m = pv[0];
    #pragma unroll
    for (int i = 1; i < VO; ++i) m = fmaxf(m, pv[i]);
    float se = 0.f;
    #pragma unroll
    for (int i = 0; i < VO; ++i) { pv[i] = __expf(pv[i] - m); se += pv[i]; }
    float inv = 1.0f / se;

    float* dstp = out + (size_t)b * VO * HWSZ + tile * TPX + tid;
    #pragma unroll
    for (int i = 0; i < VO; ++i) dstp[(size_t)i * HWSZ] = pv[i] * inv;
}

extern "C" void kernel_launch(void* const* d_in, const int* in_sizes, int n_in,
                              void* d_out, int out_size, void* d_ws, size_t ws_size,
                              hipStream_t stream) {
    const float* codeC  = (const float*)d_in[0];
    const float* codeBG = (const float*)d_in[1];
    const float* refc   = (const float*)d_in[2];
    // d_in[3] (ref_code_bg) unused by the reference
    const int* coord = (const int*)d_in[4];
    const int* cls   = (const int*)d_in[5];
    float* out = (float*)d_out;

    char* ws = (char*)d_ws;
    float* protosT  = (float*)(ws);                    // 40,960 B  [c][v]
    float* probC    = (float*)(ws + 40960);            // 4,096,000 B
    float* minvecN  = (float*)(ws + 4136960);          // 16,384 B
    u64*   batchMin = (u64*)  (ws + 4153344);          // 64 B
    float* partC    = (float*)(ws + 4153408);          // 400*21*256*4 = 8,601,600 B
    float* partBG   = (float*)(ws + 12755008);         // 400*2*256*4 = 819,200 B

    k_protos    <<<dim3(VV),          dim3(512), 0, stream>>>(refc, coord, cls, protosT, batchMin);
    k_probC_part<<<dim3(BB * NT * 2), dim3(256), 0, stream>>>(codeC, protosT, partC);
    k_finishC   <<<dim3(BB * NT),     dim3(256), 0, stream>>>(partC, probC, batchMin);
    k_minvec    <<<dim3(BB),          dim3(512), 0, stream>>>(batchMin, codeBG, minvecN);
    k_bg_part   <<<dim3(BB * NT * 2), dim3(256), 0, stream>>>(codeBG, minvecN, partBG);
    k_finishBG  <<<dim3(BB * NT),     dim3(256), 0, stream>>>(partBG, probC, out);
}